// Round 7
// baseline (226.023 us; speedup 1.0000x reference)
//
#include <hip/hip_runtime.h>
#include <hip/hip_bf16.h>

typedef __attribute__((ext_vector_type(8))) short bf16x8;
typedef __attribute__((ext_vector_type(4))) short short4v;
typedef __attribute__((ext_vector_type(4))) float f32x4;
typedef unsigned int u32;

// ---------- helpers ----------
__device__ __forceinline__ short f2bf(float f) {
    union { float f; u32 i; } c; c.f = f;
    u32 r = c.i + 0x7FFFu + ((c.i >> 16) & 1u);   // RNE
    return (short)(r >> 16);
}
__device__ __forceinline__ u32 pack2bf(float lo, float hi) {
    return ((u32)(unsigned short)f2bf(hi) << 16) | (u32)(unsigned short)f2bf(lo);
}
__device__ __forceinline__ f32x4 mfma16(bf16x8 a, bf16x8 b, f32x4 c) {
    return __builtin_amdgcn_mfma_f32_16x16x32_bf16(a, b, c, 0, 0, 0);
}
// K=16 MFMA: B-operand layout matches QK^T D-layout -> zero-shuffle PV.
__device__ __forceinline__ f32x4 mfma16k16(short4v a, short4v b, f32x4 c) {
#if __has_builtin(__builtin_amdgcn_mfma_f32_16x16x16bf16_1k)
    return __builtin_amdgcn_mfma_f32_16x16x16bf16_1k(a, b, c, 0, 0, 0);
#else
    f32x4 d = c;
    asm volatile("v_mfma_f32_16x16x16_bf16 %0, %1, %2, %0"
                 : "+v"(d) : "v"(a), "v"(b));
    return d;
#endif
}
// bare v_exp_f32 (exp2); logits are kept in log2 domain (log2e folded into Q)
__device__ __forceinline__ float fexp2(float x) {
#if __has_builtin(__builtin_amdgcn_exp2f)
    return __builtin_amdgcn_exp2f(x);
#else
    float r; asm("v_exp_f32 %0, %1" : "=v"(r) : "v"(x)); return r;
#endif
}
__device__ __forceinline__ void load_lds16(const void* g, void* l) {
    __builtin_amdgcn_global_load_lds(
        (const __attribute__((address_space(1))) u32*)g,
        (__attribute__((address_space(3))) u32*)l, 16, 0, 0);
}

// ---------- fp32 -> bf16 convert (x + 4 weights fused) ----------
__global__ __launch_bounds__(256) void cvt_all_kernel(
    const float* __restrict__ x, const float* __restrict__ wq,
    const float* __restrict__ wk, const float* __restrict__ wv,
    const float* __restrict__ wo, short* __restrict__ ws) {
    const int XV = (4096 * 1024) / 4;
    const int WV = (1024 * 1024) / 4;
    int i = blockIdx.x * 256 + threadIdx.x;
    const float4* src; short4v* dst; int off;
    if (i < XV)            { src = (const float4*)x;  dst = (short4v*)(ws);           off = i; }
    else if (i < XV + WV)  { src = (const float4*)wq; dst = (short4v*)(ws + 4194304); off = i - XV; }
    else if (i < XV + 2*WV){ src = (const float4*)wk; dst = (short4v*)(ws + 5242880); off = i - XV - WV; }
    else if (i < XV + 3*WV){ src = (const float4*)wv; dst = (short4v*)(ws + 6291456); off = i - XV - 2*WV; }
    else                   { src = (const float4*)wo; dst = (short4v*)(ws + 7340032); off = i - XV - 3*WV; }
    float4 v = src[off];
    short4v o;
    o.x = f2bf(v.x); o.y = f2bf(v.y); o.z = f2bf(v.z); o.w = f2bf(v.w);
    dst[off] = o;
}

// ---------- fused QKV projection: 64x128 tile, 1536 blocks = 6/CU ----------
// Q scaled by 0.125*log2e (folds softmax-scale AND exp->exp2 conversion).
// Q/K epilogue: LDS transpose -> 16-B coalesced stores into [bh][np][64].
// V epilogue: direct PV-fragment-order stores.
__global__ __launch_bounds__(256, 6) void gemm_qkv_kernel(
    const short* __restrict__ xb, const short* __restrict__ wqb,
    const short* __restrict__ wkb, const short* __restrict__ wvb,
    short* __restrict__ Qh, short* __restrict__ Kh, short* __restrict__ Vf) {
    __shared__ short lds[12288];   // A frags [0,4096), B frags [4096,12288)
    const int K = 1024;
    const int wave = threadIdx.x >> 6, lane = threadIdx.x & 63;
    const int lr = lane & 15, lg = lane >> 4;
    const int sel = blockIdx.x >> 3;
    const int nbase = (blockIdx.x & 7) * 128;
    const int mbase = blockIdx.y * 64;
    const short* Bm = (sel == 0) ? wqb : (sel == 1) ? wkb : wvb;
    const int wm = wave >> 1, wn = wave & 1;

    f32x4 acc[2][4];
    #pragma unroll
    for (int i = 0; i < 2; ++i)
        #pragma unroll
        for (int j = 0; j < 4; ++j) acc[i][j] = f32x4{0.f, 0.f, 0.f, 0.f};

    for (int k0 = 0; k0 < K; k0 += 64) {
        __syncthreads();
        #pragma unroll
        for (int l = 0; l < 6; ++l) {
            int f = l*4 + wave;
            if (f < 8) {
                int mt = f >> 1, kc = f & 1;
                load_lds16(xb + (size_t)(mbase + mt*16 + lr)*K + (k0 + kc*32 + lg*8),
                           lds + f*512);
            } else {
                int fb = f - 8, nt = fb >> 1, kc = fb & 1;
                load_lds16(Bm + (size_t)(nbase + nt*16 + lr)*K + (k0 + kc*32 + lg*8),
                           lds + 4096 + fb*512);
            }
        }
        __syncthreads();
        #pragma unroll
        for (int kc = 0; kc < 2; ++kc) {
            bf16x8 af[2], bfv[4];
            #pragma unroll
            for (int mi = 0; mi < 2; ++mi)
                af[mi] = *(const bf16x8*)(lds + ((wm*2 + mi)*2 + kc)*512 + lane*8);
            #pragma unroll
            for (int ni = 0; ni < 4; ++ni)
                bfv[ni] = *(const bf16x8*)(lds + 4096 + ((wn*4 + ni)*2 + kc)*512 + lane*8);
            #pragma unroll
            for (int mi = 0; mi < 2; ++mi)
                #pragma unroll
                for (int ni = 0; ni < 4; ++ni)
                    acc[mi][ni] = mfma16(af[mi], bfv[ni], acc[mi][ni]);
        }
    }

    if (sel == 2) {
        #pragma unroll
        for (int mi = 0; mi < 2; ++mi) {
            int m0 = mbase + wm*32 + mi*16 + lg*4;
            #pragma unroll
            for (int ni = 0; ni < 4; ++ni) {
                int nc = nbase + wn*64 + ni*16 + lr;
                int h = nc >> 6, d = nc & 63;
                f32x4 v = acc[mi][ni];
                int bi = m0 >> 11, np = m0 & 2047;
                int c = np >> 6, s = (np >> 4) & 3, lg2 = (np >> 2) & 3;
                int dc = d >> 4, lr2 = d & 15;
                size_t off = ((size_t)(bi*16 + h)*32 + c)*4096
                           + (size_t)((s*4 + dc)*64 + lg2*16 + lr2)*4;
                short4v o;
                o.x = f2bf(v.x); o.y = f2bf(v.y); o.z = f2bf(v.z); o.w = f2bf(v.w);
                *(short4v*)&Vf[off] = o;
            }
        }
    } else {
        short* dstb = (sel == 0) ? Qh : Kh;
        const float sc = (sel == 0) ? 0.125f * 1.44269504f : 1.0f;
        __syncthreads();   // mainloop LDS reads done before overwrite
        #pragma unroll
        for (int mi = 0; mi < 2; ++mi) {
            int row0 = wm*32 + mi*16 + lg*4;
            #pragma unroll
            for (int ni = 0; ni < 4; ++ni) {
                int col = wn*64 + ni*16 + lr;
                f32x4 v = acc[mi][ni];
                #pragma unroll
                for (int r = 0; r < 4; ++r)
                    lds[(row0 + r)*132 + col] = f2bf(v[r] * sc);
            }
        }
        __syncthreads();
        const int h0 = nbase >> 6;
        const int tid = threadIdx.x;
        #pragma unroll
        for (int it = 0; it < 4; ++it) {
            int g = it*256 + tid;          // 0..1023
            int np_l = g >> 4;             // 0..63
            int t16 = g & 15;
            int P = t16 >> 3;              // head panel 0/1
            int c8 = (t16 & 7) * 8;        // col in shorts
            bf16x8 val = *(const bf16x8*)&lds[np_l*132 + P*64 + c8];
            int m = mbase + np_l; int bi = m >> 11, np = m & 2047;
            *(bf16x8*)&dstb[((size_t)(bi*16 + h0 + P)*2048 + np)*64 + c8] = val;
        }
    }
}

// ---------- output projection: 64x128 tile (512 blocks = 2/CU) ----------
__global__ __launch_bounds__(256) void gemm_out_kernel(
    const short* __restrict__ AO, const short* __restrict__ wob,
    const float* __restrict__ bias, float* __restrict__ out) {
    __shared__ short lds[12288];
    const int K = 1024;
    const int wave = threadIdx.x >> 6, lane = threadIdx.x & 63;
    const int lr = lane & 15, lg = lane >> 4;
    const int nbase = blockIdx.x * 128;
    const int mbase = blockIdx.y * 64;
    const int wm = wave >> 1, wn = wave & 1;

    f32x4 acc[2][4];
    #pragma unroll
    for (int i = 0; i < 2; ++i)
        #pragma unroll
        for (int j = 0; j < 4; ++j) acc[i][j] = f32x4{0.f, 0.f, 0.f, 0.f};

    for (int k0 = 0; k0 < K; k0 += 64) {
        __syncthreads();
        #pragma unroll
        for (int l = 0; l < 6; ++l) {
            int f = l*4 + wave;
            if (f < 8) {
                int mt = f >> 1, kc = f & 1;
                load_lds16(AO + (size_t)(mbase + mt*16 + lr)*K + (k0 + kc*32 + lg*8),
                           lds + f*512);
            } else {
                int fb = f - 8, nt = fb >> 1, kc = fb & 1;
                load_lds16(wob + (size_t)(nbase + nt*16 + lr)*K + (k0 + kc*32 + lg*8),
                           lds + 4096 + fb*512);
            }
        }
        __syncthreads();
        #pragma unroll
        for (int kc = 0; kc < 2; ++kc) {
            bf16x8 af[2], bfv[4];
            #pragma unroll
            for (int mi = 0; mi < 2; ++mi)
                af[mi] = *(const bf16x8*)(lds + ((wm*2 + mi)*2 + kc)*512 + lane*8);
            #pragma unroll
            for (int ni = 0; ni < 4; ++ni)
                bfv[ni] = *(const bf16x8*)(lds + 4096 + ((wn*4 + ni)*2 + kc)*512 + lane*8);
            #pragma unroll
            for (int mi = 0; mi < 2; ++mi)
                #pragma unroll
                for (int ni = 0; ni < 4; ++ni)
                    acc[mi][ni] = mfma16(af[mi], bfv[ni], acc[mi][ni]);
        }
    }

    #pragma unroll
    for (int mi = 0; mi < 2; ++mi) {
        int m0 = mbase + wm*32 + mi*16 + lg*4;
        #pragma unroll
        for (int ni = 0; ni < 4; ++ni) {
            int nc = nbase + wn*64 + ni*16 + lr;
            float bj = bias[nc];
            f32x4 v = acc[mi][ni];
            #pragma unroll
            for (int r = 0; r < 4; ++r)
                out[(size_t)(m0 + r)*1024 + nc] = v[r] + bj;
        }
    }
}

// ---------- dual-tile LDS-staged adaptive-temperature attention ----------
// Block = 2 waves (32 q-rows), owns tile pair (tA=63-pr, tB=pr) of 32-row
// q-tiles and processes BOTH in one chunk sweep (B's subtiles are a subset of
// A's) -> K/V staging and barriers paid once per pair. 1024 blocks = 4
// barrier-groups/CU. Logits in log2 domain (log2e folded into Q by qkv):
// s = sum 2^d, H = ln2*(log2 s - t2/s), P = exp2(beta*d). Zero-shuffle PV.
__global__ __launch_bounds__(128) void attn_kernel(
    const short* __restrict__ Qh, const short* __restrict__ Kh,
    const short* __restrict__ Vf, short* __restrict__ AO) {
    __shared__ short lds[16384];   // K bufs [0,8192), V bufs [8192,16384)
    const int lane = threadIdx.x & 63;
    const int wave = threadIdx.x >> 6;       // 0..1
    const int lr = lane & 15, lg = lane >> 4;
    const int bid  = blockIdx.x;             // 0..1023
    const int xcd  = bid & 7;
    const int rest = bid >> 3;               // 0..127
    const int pr   = rest >> 2;              // 0..31, heavy pairs first (LPT)
    const int bh   = ((rest & 3) << 3) | xcd;
    const int b = bh >> 4, h = bh & 15;
    const int tA = 63 - pr, tB = pr;         // 32-row tile indices, tB < tA
    const int qbA = tA*32 + wave*16, qaA = qbA + lr;
    const int qbB = tB*32 + wave*16, qaB = qbB + lr;
    const int u2 = tA >> 1;                  // shared sweep: chunks 0..u2
    const short* Q  = Qh + (size_t)bh * (2048 * 64);
    const short* Kg = Kh + (size_t)bh * (2048 * 64);
    const short* Vg = Vf + (size_t)bh * (32 * 4096);

    bf16x8 qfA0 = *(const bf16x8*)&Q[(size_t)qaA*64 + lg*8];
    bf16x8 qfA1 = *(const bf16x8*)&Q[(size_t)qaA*64 + 32 + lg*8];
    bf16x8 qfB0 = *(const bf16x8*)&Q[(size_t)qaB*64 + lg*8];
    bf16x8 qfB1 = *(const bf16x8*)&Q[(size_t)qaB*64 + 32 + lg*8];

    const int fc0 = wave * 4;   // this wave's 4 staging slots (of 8)

    auto stageK = [&](int buf, int c) {
        #pragma unroll
        for (int i = 0; i < 4; ++i) {
            int fc = fc0 + i, s = fc >> 1, ch = fc & 1;
            load_lds16(Kg + ((size_t)(c*64 + s*16 + lr)*64 + ch*32 + lg*8),
                       &lds[buf*4096 + fc*512]);
        }
    };
    auto stageV = [&](int buf, int c) {
        #pragma unroll
        for (int i = 0; i < 4; ++i) {
            int fi = fc0 + i;
            load_lds16(Vg + (size_t)c*4096 + fi*512 + lane*8,
                       &lds[8192 + buf*4096 + fi*512]);
        }
    };

    // ================= pass 1: entropy stats (both tiles) =================
    float sA = 0.f, t2A = 0.f, sB = 0.f, t2B = 0.f;
    stageK(0, 0);
    #pragma unroll 1
    for (int c = 0; c <= u2; ++c) {
        __syncthreads();
        if (c < u2) stageK((c + 1) & 1, c + 1);
        const int base = (c & 1) * 4096;
        #pragma unroll
        for (int s = 0; s < 4; ++s) {
            const int k0 = c*64 + s*16;
            if (k0 > qbA) continue;            // wave-uniform
            bf16x8 kf0 = *(const bf16x8*)&lds[base + (s*2    )*512 + lane*8];
            bf16x8 kf1 = *(const bf16x8*)&lds[base + (s*2 + 1)*512 + lane*8];
            f32x4 d = {0.f,0.f,0.f,0.f};
            d = mfma16(kf0, qfA0, d); d = mfma16(kf1, qfA1, d);
            if (k0 < qbA) {
                #pragma unroll
                for (int r = 0; r < 4; ++r) {
                    float e = fexp2(d[r]); sA += e; t2A += e * d[r];
                }
            } else {
                int kb = k0 + lg*4;
                #pragma unroll
                for (int r = 0; r < 4; ++r) {
                    float dd = (kb + r <= qaA) ? d[r] : -1e30f;
                    float e = fexp2(dd); sA += e; t2A += e * dd;
                }
            }
            if (k0 <= qbB) {
                f32x4 d2 = {0.f,0.f,0.f,0.f};
                d2 = mfma16(kf0, qfB0, d2); d2 = mfma16(kf1, qfB1, d2);
                if (k0 < qbB) {
                    #pragma unroll
                    for (int r = 0; r < 4; ++r) {
                        float e = fexp2(d2[r]); sB += e; t2B += e * d2[r];
                    }
                } else {
                    int kb = k0 + lg*4;
                    #pragma unroll
                    for (int r = 0; r < 4; ++r) {
                        float dd = (kb + r <= qaB) ? d2[r] : -1e30f;
                        float e = fexp2(dd); sB += e; t2B += e * dd;
                    }
                }
            }
        }
    }
    sA += __shfl_xor(sA, 16); t2A += __shfl_xor(t2A, 16);
    sA += __shfl_xor(sA, 32); t2A += __shfl_xor(t2A, 32);
    sB += __shfl_xor(sB, 16); t2B += __shfl_xor(t2B, 16);
    sB += __shfl_xor(sB, 32); t2B += __shfl_xor(t2B, 32);
    const float LN2 = 0.69314718f;
    float HA = LN2 * (__log2f(sA) - t2A / sA);
    float HB = LN2 * (__log2f(sB) - t2B / sB);
    float betaA = 1.f, betaB = 1.f;
    if (HA > 0.5f)
        betaA = fmaxf((((-0.037f*HA + 0.481f)*HA - 2.3f)*HA + 4.917f)*HA - 1.791f, 1.f);
    if (HB > 0.5f)
        betaB = fmaxf((((-0.037f*HB + 0.481f)*HB - 2.3f)*HB + 4.917f)*HB - 1.791f, 1.f);

    // ================= pass 2: softmax(beta*d) and PV (both tiles) ==========
    f32x4 oA0 = {0.f,0.f,0.f,0.f}, oA1 = {0.f,0.f,0.f,0.f};
    f32x4 oA2 = {0.f,0.f,0.f,0.f}, oA3 = {0.f,0.f,0.f,0.f};
    f32x4 oB0 = {0.f,0.f,0.f,0.f}, oB1 = {0.f,0.f,0.f,0.f};
    f32x4 oB2 = {0.f,0.f,0.f,0.f}, oB3 = {0.f,0.f,0.f,0.f};
    float s2A = 0.f, s2B = 0.f;
    __syncthreads();                          // pass-1 reads done; reuse bufs
    stageK(0, 0); stageV(0, 0);
    #pragma unroll 1
    for (int c = 0; c <= u2; ++c) {
        __syncthreads();
        if (c < u2) { stageK((c + 1) & 1, c + 1); stageV((c + 1) & 1, c + 1); }
        const int kb_ = (c & 1) * 4096;
        const int vb_ = 8192 + (c & 1) * 4096;
        #pragma unroll
        for (int s = 0; s < 4; ++s) {
            const int k0 = c*64 + s*16;
            if (k0 > qbA) continue;
            bf16x8 kf0 = *(const bf16x8*)&lds[kb_ + (s*2    )*512 + lane*8];
            bf16x8 kf1 = *(const bf16x8*)&lds[kb_ + (s*2 + 1)*512 + lane*8];
            short4v vf0 = *(const short4v*)&lds[vb_ + ((s*4 + 0)*64 + lane)*4];
            short4v vf1 = *(const short4v*)&lds[vb_ + ((s*4 + 1)*64 + lane)*4];
            short4v vf2 = *(const short4v*)&lds[vb_ + ((s*4 + 2)*64 + lane)*4];
            short4v vf3 = *(const short4v*)&lds[vb_ + ((s*4 + 3)*64 + lane)*4];
            f32x4 d = {0.f,0.f,0.f,0.f};
            d = mfma16(kf0, qfA0, d); d = mfma16(kf1, qfA1, d);
            float pv[4];
            if (k0 < qbA) {
                #pragma unroll
                for (int r = 0; r < 4; ++r) { pv[r] = fexp2(betaA * d[r]); s2A += pv[r]; }
            } else {
                int kb = k0 + lg*4;
                #pragma unroll
                for (int r = 0; r < 4; ++r) {
                    float dd = (kb + r <= qaA) ? d[r] : -1e30f;
                    pv[r] = fexp2(betaA * dd); s2A += pv[r];
                }
            }
            union { short4v s4; u32 uu[2]; } pb;
            pb.uu[0] = pack2bf(pv[0], pv[1]);
            pb.uu[1] = pack2bf(pv[2], pv[3]);
            oA0 = mfma16k16(vf0, pb.s4, oA0);
            oA1 = mfma16k16(vf1, pb.s4, oA1);
            oA2 = mfma16k16(vf2, pb.s4, oA2);
            oA3 = mfma16k16(vf3, pb.s4, oA3);
            if (k0 <= qbB) {
                f32x4 d2 = {0.f,0.f,0.f,0.f};
                d2 = mfma16(kf0, qfB0, d2); d2 = mfma16(kf1, qfB1, d2);
                if (k0 < qbB) {
                    #pragma unroll
                    for (int r = 0; r < 4; ++r) { pv[r] = fexp2(betaB * d2[r]); s2B += pv[r]; }
                } else {
                    int kb = k0 + lg*4;
                    #pragma unroll
                    for (int r = 0; r < 4; ++r) {
                        float dd = (kb + r <= qaB) ? d2[r] : -1e30f;
                        pv[r] = fexp2(betaB * dd); s2B += pv[r];
                    }
                }
                union { short4v s4; u32 uu[2]; } pb2;
                pb2.uu[0] = pack2bf(pv[0], pv[1]);
                pb2.uu[1] = pack2bf(pv[2], pv[3]);
                oB0 = mfma16k16(vf0, pb2.s4, oB0);
                oB1 = mfma16k16(vf1, pb2.s4, oB1);
                oB2 = mfma16k16(vf2, pb2.s4, oB2);
                oB3 = mfma16k16(vf3, pb2.s4, oB3);
            }
        }
    }
    s2A += __shfl_xor(s2A, 16); s2A += __shfl_xor(s2A, 32);
    s2B += __shfl_xor(s2B, 16); s2B += __shfl_xor(s2B, 32);
    float invA = 1.f / s2A, invB = 1.f / s2B;

    size_t rowA = ((size_t)(b*2048 + qaA))*1024 + h*64;
    size_t rowB = ((size_t)(b*2048 + qaB))*1024 + h*64;
    f32x4 ooA[4] = {oA0, oA1, oA2, oA3};
    f32x4 ooB[4] = {oB0, oB1, oB2, oB3};
    #pragma unroll
    for (int dc = 0; dc < 4; ++dc) {
        short4v wa, wb;
        #pragma unroll
        for (int r = 0; r < 4; ++r) {
            wa[r] = f2bf(ooA[dc][r] * invA);
            wb[r] = f2bf(ooB[dc][r] * invB);
        }
        *(short4v*)&AO[rowA + dc*16 + lg*4] = wa;
        *(short4v*)&AO[rowB + dc*16 + lg*4] = wb;
    }
}

// ---------- launch ----------
extern "C" void kernel_launch(void* const* d_in, const int* in_sizes, int n_in,
                              void* d_out, int out_size, void* d_ws, size_t ws_size,
                              hipStream_t stream) {
    const float* x  = (const float*)d_in[0];
    const float* Wq = (const float*)d_in[1];
    const float* Wk = (const float*)d_in[2];
    const float* Wv = (const float*)d_in[3];
    const float* Wo = (const float*)d_in[4];
    const float* bo = (const float*)d_in[5];
    float* out = (float*)d_out;
    short* ws = (short*)d_ws;

    short* xb  = ws;              // [4096][1024] bf16 x
    short* wqb = ws + 4194304;
    short* wkb = ws + 5242880;
    short* wvb = ws + 6291456;
    short* wob = ws + 7340032;
    short* Qh  = ws + 8388608;    // [2][16][2048][64], scaled 0.125*log2e
    short* Kh  = ws + 12582912;   // [2][16][2048][64]
    short* Vf  = ws + 16777216;   // [32 bh][32 chunks][4096] PV-fragment order
    short* AO  = ws + 20971520;   // [4096][1024] attention output

    cvt_all_kernel<<<8192, 256, 0, stream>>>(x, Wq, Wk, Wv, Wo, ws);
    gemm_qkv_kernel<<<dim3(24, 64), 256, 0, stream>>>(xb, wqb, wkb, wvb, Qh, Kh, Vf);
    attn_kernel<<<1024, 128, 0, stream>>>(Qh, Kh, Vf, AO);
    gemm_out_kernel<<<dim3(8, 64), 256, 0, stream>>>(AO, wob, bo, out);
}

// Round 8
// 164.283 us; speedup vs baseline: 1.3758x; 1.3758x over previous
//
#include <hip/hip_runtime.h>
#include <hip/hip_bf16.h>

typedef __attribute__((ext_vector_type(8))) short bf16x8;
typedef __attribute__((ext_vector_type(4))) short short4v;
typedef __attribute__((ext_vector_type(4))) float f32x4;
typedef unsigned int u32;

// ---------- helpers ----------
__device__ __forceinline__ short f2bf(float f) {
    union { float f; u32 i; } c; c.f = f;
    u32 r = c.i + 0x7FFFu + ((c.i >> 16) & 1u);   // RNE
    return (short)(r >> 16);
}
__device__ __forceinline__ u32 pack2bf(float lo, float hi) {
    return ((u32)(unsigned short)f2bf(hi) << 16) | (u32)(unsigned short)f2bf(lo);
}
__device__ __forceinline__ f32x4 mfma16(bf16x8 a, bf16x8 b, f32x4 c) {
    return __builtin_amdgcn_mfma_f32_16x16x32_bf16(a, b, c, 0, 0, 0);
}
// K=16 MFMA: B-operand layout matches QK^T D-layout -> zero-shuffle PV.
__device__ __forceinline__ f32x4 mfma16k16(short4v a, short4v b, f32x4 c) {
#if __has_builtin(__builtin_amdgcn_mfma_f32_16x16x16bf16_1k)
    return __builtin_amdgcn_mfma_f32_16x16x16bf16_1k(a, b, c, 0, 0, 0);
#else
    f32x4 d = c;
    asm volatile("v_mfma_f32_16x16x16_bf16 %0, %1, %2, %0"
                 : "+v"(d) : "v"(a), "v"(b));
    return d;
#endif
}
// bare v_exp_f32 (exp2); logits kept in log2 domain (log2e folded into Q)
__device__ __forceinline__ float fexp2(float x) {
#if __has_builtin(__builtin_amdgcn_exp2f)
    return __builtin_amdgcn_exp2f(x);
#else
    float r; asm("v_exp_f32 %0, %1" : "=v"(r) : "v"(x)); return r;
#endif
}
__device__ __forceinline__ void load_lds16(const void* g, void* l) {
    __builtin_amdgcn_global_load_lds(
        (const __attribute__((address_space(1))) u32*)g,
        (__attribute__((address_space(3))) u32*)l, 16, 0, 0);
}

// ---------- fp32 -> bf16 convert (x + 4 weights fused) ----------
__global__ __launch_bounds__(256) void cvt_all_kernel(
    const float* __restrict__ x, const float* __restrict__ wq,
    const float* __restrict__ wk, const float* __restrict__ wv,
    const float* __restrict__ wo, short* __restrict__ ws) {
    const int XV = (4096 * 1024) / 4;
    const int WV = (1024 * 1024) / 4;
    int i = blockIdx.x * 256 + threadIdx.x;
    const float4* src; short4v* dst; int off;
    if (i < XV)            { src = (const float4*)x;  dst = (short4v*)(ws);           off = i; }
    else if (i < XV + WV)  { src = (const float4*)wq; dst = (short4v*)(ws + 4194304); off = i - XV; }
    else if (i < XV + 2*WV){ src = (const float4*)wk; dst = (short4v*)(ws + 5242880); off = i - XV - WV; }
    else if (i < XV + 3*WV){ src = (const float4*)wv; dst = (short4v*)(ws + 6291456); off = i - XV - 2*WV; }
    else                   { src = (const float4*)wo; dst = (short4v*)(ws + 7340032); off = i - XV - 3*WV; }
    float4 v = src[off];
    short4v o;
    o.x = f2bf(v.x); o.y = f2bf(v.y); o.z = f2bf(v.z); o.w = f2bf(v.w);
    dst[off] = o;
}

// ---------- fused QKV projection: 64x128 tile ----------
// NOTE: plain __launch_bounds__(256). The (256,6) pin in R7 capped VGPR at 40
// and spilled the accumulators to scratch (WRITE_SIZE 24.5MB -> 303MB).
// Q scaled by 0.125*log2e (folds softmax scale AND exp->exp2 conversion).
__global__ __launch_bounds__(256) void gemm_qkv_kernel(
    const short* __restrict__ xb, const short* __restrict__ wqb,
    const short* __restrict__ wkb, const short* __restrict__ wvb,
    short* __restrict__ Qh, short* __restrict__ Kh, short* __restrict__ Vf) {
    __shared__ short lds[12288];   // A frags [0,4096), B frags [4096,12288)
    const int K = 1024;
    const int wave = threadIdx.x >> 6, lane = threadIdx.x & 63;
    const int lr = lane & 15, lg = lane >> 4;
    const int sel = blockIdx.x >> 3;
    const int nbase = (blockIdx.x & 7) * 128;
    const int mbase = blockIdx.y * 64;
    const short* Bm = (sel == 0) ? wqb : (sel == 1) ? wkb : wvb;
    const int wm = wave >> 1, wn = wave & 1;

    f32x4 acc[2][4];
    #pragma unroll
    for (int i = 0; i < 2; ++i)
        #pragma unroll
        for (int j = 0; j < 4; ++j) acc[i][j] = f32x4{0.f, 0.f, 0.f, 0.f};

    for (int k0 = 0; k0 < K; k0 += 64) {
        __syncthreads();
        #pragma unroll
        for (int l = 0; l < 6; ++l) {
            int f = l*4 + wave;
            if (f < 8) {
                int mt = f >> 1, kc = f & 1;
                load_lds16(xb + (size_t)(mbase + mt*16 + lr)*K + (k0 + kc*32 + lg*8),
                           lds + f*512);
            } else {
                int fb = f - 8, nt = fb >> 1, kc = fb & 1;
                load_lds16(Bm + (size_t)(nbase + nt*16 + lr)*K + (k0 + kc*32 + lg*8),
                           lds + 4096 + fb*512);
            }
        }
        __syncthreads();
        #pragma unroll
        for (int kc = 0; kc < 2; ++kc) {
            bf16x8 af[2], bfv[4];
            #pragma unroll
            for (int mi = 0; mi < 2; ++mi)
                af[mi] = *(const bf16x8*)(lds + ((wm*2 + mi)*2 + kc)*512 + lane*8);
            #pragma unroll
            for (int ni = 0; ni < 4; ++ni)
                bfv[ni] = *(const bf16x8*)(lds + 4096 + ((wn*4 + ni)*2 + kc)*512 + lane*8);
            #pragma unroll
            for (int mi = 0; mi < 2; ++mi)
                #pragma unroll
                for (int ni = 0; ni < 4; ++ni)
                    acc[mi][ni] = mfma16(af[mi], bfv[ni], acc[mi][ni]);
        }
    }

    if (sel == 2) {
        #pragma unroll
        for (int mi = 0; mi < 2; ++mi) {
            int m0 = mbase + wm*32 + mi*16 + lg*4;
            #pragma unroll
            for (int ni = 0; ni < 4; ++ni) {
                int nc = nbase + wn*64 + ni*16 + lr;
                int h = nc >> 6, d = nc & 63;
                f32x4 v = acc[mi][ni];
                int bi = m0 >> 11, np = m0 & 2047;
                int c = np >> 6, s = (np >> 4) & 3, lg2 = (np >> 2) & 3;
                int dc = d >> 4, lr2 = d & 15;
                size_t off = ((size_t)(bi*16 + h)*32 + c)*4096
                           + (size_t)((s*4 + dc)*64 + lg2*16 + lr2)*4;
                short4v o;
                o.x = f2bf(v.x); o.y = f2bf(v.y); o.z = f2bf(v.z); o.w = f2bf(v.w);
                *(short4v*)&Vf[off] = o;
            }
        }
    } else {
        short* dstb = (sel == 0) ? Qh : Kh;
        const float sc = (sel == 0) ? 0.125f * 1.44269504f : 1.0f;
        __syncthreads();   // mainloop LDS reads done before overwrite
        #pragma unroll
        for (int mi = 0; mi < 2; ++mi) {
            int row0 = wm*32 + mi*16 + lg*4;
            #pragma unroll
            for (int ni = 0; ni < 4; ++ni) {
                int col = wn*64 + ni*16 + lr;
                f32x4 v = acc[mi][ni];
                #pragma unroll
                for (int r = 0; r < 4; ++r)
                    lds[(row0 + r)*132 + col] = f2bf(v[r] * sc);
            }
        }
        __syncthreads();
        const int h0 = nbase >> 6;
        const int tid = threadIdx.x;
        #pragma unroll
        for (int it = 0; it < 4; ++it) {
            int g = it*256 + tid;          // 0..1023
            int np_l = g >> 4;             // 0..63
            int t16 = g & 15;
            int P = t16 >> 3;              // head panel 0/1
            int c8 = (t16 & 7) * 8;        // col in shorts
            bf16x8 val = *(const bf16x8*)&lds[np_l*132 + P*64 + c8];
            int m = mbase + np_l; int bi = m >> 11, np = m & 2047;
            *(bf16x8*)&dstb[((size_t)(bi*16 + h0 + P)*2048 + np)*64 + c8] = val;
        }
    }
}

// ---------- output projection: 64x128 tile (512 blocks = 2/CU) ----------
__global__ __launch_bounds__(256) void gemm_out_kernel(
    const short* __restrict__ AO, const short* __restrict__ wob,
    const float* __restrict__ bias, float* __restrict__ out) {
    __shared__ short lds[12288];
    const int K = 1024;
    const int wave = threadIdx.x >> 6, lane = threadIdx.x & 63;
    const int lr = lane & 15, lg = lane >> 4;
    const int nbase = blockIdx.x * 128;
    const int mbase = blockIdx.y * 64;
    const int wm = wave >> 1, wn = wave & 1;

    f32x4 acc[2][4];
    #pragma unroll
    for (int i = 0; i < 2; ++i)
        #pragma unroll
        for (int j = 0; j < 4; ++j) acc[i][j] = f32x4{0.f, 0.f, 0.f, 0.f};

    for (int k0 = 0; k0 < K; k0 += 64) {
        __syncthreads();
        #pragma unroll
        for (int l = 0; l < 6; ++l) {
            int f = l*4 + wave;
            if (f < 8) {
                int mt = f >> 1, kc = f & 1;
                load_lds16(AO + (size_t)(mbase + mt*16 + lr)*K + (k0 + kc*32 + lg*8),
                           lds + f*512);
            } else {
                int fb = f - 8, nt = fb >> 1, kc = fb & 1;
                load_lds16(wob + (size_t)(nbase + nt*16 + lr)*K + (k0 + kc*32 + lg*8),
                           lds + 4096 + fb*512);
            }
        }
        __syncthreads();
        #pragma unroll
        for (int kc = 0; kc < 2; ++kc) {
            bf16x8 af[2], bfv[4];
            #pragma unroll
            for (int mi = 0; mi < 2; ++mi)
                af[mi] = *(const bf16x8*)(lds + ((wm*2 + mi)*2 + kc)*512 + lane*8);
            #pragma unroll
            for (int ni = 0; ni < 4; ++ni)
                bfv[ni] = *(const bf16x8*)(lds + 4096 + ((wn*4 + ni)*2 + kc)*512 + lane*8);
            #pragma unroll
            for (int mi = 0; mi < 2; ++mi)
                #pragma unroll
                for (int ni = 0; ni < 4; ++ni)
                    acc[mi][ni] = mfma16(af[mi], bfv[ni], acc[mi][ni]);
        }
    }

    #pragma unroll
    for (int mi = 0; mi < 2; ++mi) {
        int m0 = mbase + wm*32 + mi*16 + lg*4;
        #pragma unroll
        for (int ni = 0; ni < 4; ++ni) {
            int nc = nbase + wn*64 + ni*16 + lr;
            float bj = bias[nc];
            f32x4 v = acc[mi][ni];
            #pragma unroll
            for (int r = 0; r < 4; ++r)
                out[(size_t)(m0 + r)*1024 + nc] = v[r] + bj;
        }
    }
}

// ---------- LDS-staged 2-pass adaptive-temperature attention (R6 struct) ----
// Block = 64 q-rows (4 waves x 16), 64-k chunks shared via LDS, async
// global_load_lds double buffers, LPT dispatch. Logits in log2 domain:
// s = sum 2^d, H = ln2*(log2 s - t2/s), P = exp2(beta*d). Zero-shuffle PV.
__global__ __launch_bounds__(256, 4) void attn_kernel(
    const short* __restrict__ Qh, const short* __restrict__ Kh,
    const short* __restrict__ Vf, short* __restrict__ AO) {
    __shared__ short lds[16384];   // K bufs [0,8192), V bufs [8192,16384)
    const int lane = threadIdx.x & 63;
    const int wave = threadIdx.x >> 6;
    const int lr = lane & 15, lg = lane >> 4;
    const int bid  = blockIdx.x;             // 0..1023
    const int xcd  = bid & 7;
    const int rest = bid >> 3;               // 0..127
    const int u    = 31 - (rest >> 2);       // heavy q-tiles dispatch first
    const int bh   = ((rest & 3) << 3) | xcd;
    const int b = bh >> 4, h = bh & 15;
    const int qbase = u*64 + wave*16;
    const int qa = qbase + lr;
    const short* Q  = Qh + (size_t)bh * (2048 * 64);
    const short* Kg = Kh + (size_t)bh * (2048 * 64);
    const short* Vg = Vf + (size_t)bh * (32 * 4096);

    bf16x8 qf0 = *(const bf16x8*)&Q[(size_t)qa*64 + lg*8];
    bf16x8 qf1 = *(const bf16x8*)&Q[(size_t)qa*64 + 32 + lg*8];

    const int fc0 = wave * 2;   // this wave's staging slots

    auto stageK = [&](int buf, int c) {
        #pragma unroll
        for (int i = 0; i < 2; ++i) {
            int fc = fc0 + i, s = fc >> 1, ch = fc & 1;
            load_lds16(Kg + ((size_t)(c*64 + s*16 + lr)*64 + ch*32 + lg*8),
                       &lds[buf*4096 + fc*512]);
        }
    };
    auto stageV = [&](int buf, int c) {
        #pragma unroll
        for (int i = 0; i < 2; ++i) {
            int fi = fc0 + i;
            load_lds16(Vg + (size_t)c*4096 + fi*512 + lane*8,
                       &lds[8192 + buf*4096 + fi*512]);
        }
    };

    // ================= pass 1: entropy stats =================
    float sm = 0.f, t2m = 0.f;
    stageK(0, 0);
    #pragma unroll 1
    for (int c = 0; c <= u; ++c) {
        __syncthreads();                       // buf[c&1] ready
        if (c < u) stageK((c + 1) & 1, c + 1); // async, hidden under compute
        const int base = (c & 1) * 4096;
        #pragma unroll
        for (int s = 0; s < 4; ++s) {
            int k0 = c*64 + s*16;
            if (k0 <= qbase) {                 // wave-uniform
                bf16x8 kf0 = *(const bf16x8*)&lds[base + (s*2    )*512 + lane*8];
                bf16x8 kf1 = *(const bf16x8*)&lds[base + (s*2 + 1)*512 + lane*8];
                f32x4 d = {0.f,0.f,0.f,0.f};
                d = mfma16(kf0, qf0, d); d = mfma16(kf1, qf1, d);
                if (k0 < qbase) {
                    #pragma unroll
                    for (int r = 0; r < 4; ++r) {
                        float e = fexp2(d[r]); sm += e; t2m += e * d[r];
                    }
                } else {                       // diagonal subtile
                    int kb = k0 + lg*4;
                    #pragma unroll
                    for (int r = 0; r < 4; ++r) {
                        float dd = (kb + r <= qa) ? d[r] : -1e30f;
                        float e = fexp2(dd); sm += e; t2m += e * dd;
                    }
                }
            }
        }
    }
    sm += __shfl_xor(sm, 16); t2m += __shfl_xor(t2m, 16);
    sm += __shfl_xor(sm, 32); t2m += __shfl_xor(t2m, 32);
    const float LN2 = 0.69314718f;
    float H = LN2 * (__log2f(sm) - t2m / sm);
    float beta = 1.f;
    if (H > 0.5f)
        beta = fmaxf((((-0.037f*H + 0.481f)*H - 2.3f)*H + 4.917f)*H - 1.791f, 1.f);

    // ================= pass 2: softmax(beta*d) and PV =================
    f32x4 o0 = {0.f,0.f,0.f,0.f}, o1 = {0.f,0.f,0.f,0.f};
    f32x4 o2 = {0.f,0.f,0.f,0.f}, o3 = {0.f,0.f,0.f,0.f};
    float s2 = 0.f;
    __syncthreads();                           // pass-1 reads done; reuse bufs
    stageK(0, 0); stageV(0, 0);
    #pragma unroll 1
    for (int c = 0; c <= u; ++c) {
        __syncthreads();
        if (c < u) { stageK((c + 1) & 1, c + 1); stageV((c + 1) & 1, c + 1); }
        const int kb_ = (c & 1) * 4096;
        const int vb_ = 8192 + (c & 1) * 4096;
        #pragma unroll
        for (int s = 0; s < 4; ++s) {
            int k0 = c*64 + s*16;
            if (k0 <= qbase) {
                bf16x8 kf0 = *(const bf16x8*)&lds[kb_ + (s*2    )*512 + lane*8];
                bf16x8 kf1 = *(const bf16x8*)&lds[kb_ + (s*2 + 1)*512 + lane*8];
                f32x4 d = {0.f,0.f,0.f,0.f};
                d = mfma16(kf0, qf0, d); d = mfma16(kf1, qf1, d);
                float pv[4];
                if (k0 < qbase) {
                    #pragma unroll
                    for (int r = 0; r < 4; ++r) { pv[r] = fexp2(beta * d[r]); s2 += pv[r]; }
                } else {
                    int kb = k0 + lg*4;
                    #pragma unroll
                    for (int r = 0; r < 4; ++r) {
                        float dd = (kb + r <= qa) ? d[r] : -1e30f;
                        pv[r] = fexp2(beta * dd); s2 += pv[r];
                    }
                }
                union { short4v s4; u32 uu[2]; } pb;
                pb.uu[0] = pack2bf(pv[0], pv[1]);
                pb.uu[1] = pack2bf(pv[2], pv[3]);
                short4v vf0 = *(const short4v*)&lds[vb_ + ((s*4 + 0)*64 + lane)*4];
                short4v vf1 = *(const short4v*)&lds[vb_ + ((s*4 + 1)*64 + lane)*4];
                short4v vf2 = *(const short4v*)&lds[vb_ + ((s*4 + 2)*64 + lane)*4];
                short4v vf3 = *(const short4v*)&lds[vb_ + ((s*4 + 3)*64 + lane)*4];
                o0 = mfma16k16(vf0, pb.s4, o0);
                o1 = mfma16k16(vf1, pb.s4, o1);
                o2 = mfma16k16(vf2, pb.s4, o2);
                o3 = mfma16k16(vf3, pb.s4, o3);
            }
        }
    }
    s2 += __shfl_xor(s2, 16); s2 += __shfl_xor(s2, 32);
    float inv = 1.f / s2;

    size_t row = ((size_t)(b*2048 + qa))*1024 + h*64;
    f32x4 oo[4] = {o0, o1, o2, o3};
    #pragma unroll
    for (int dc = 0; dc < 4; ++dc) {
        short4v wv;
        #pragma unroll
        for (int r = 0; r < 4; ++r) wv[r] = f2bf(oo[dc][r] * inv);
        *(short4v*)&AO[row + dc*16 + lg*4] = wv;
    }
}

// ---------- launch ----------
extern "C" void kernel_launch(void* const* d_in, const int* in_sizes, int n_in,
                              void* d_out, int out_size, void* d_ws, size_t ws_size,
                              hipStream_t stream) {
    const float* x  = (const float*)d_in[0];
    const float* Wq = (const float*)d_in[1];
    const float* Wk = (const float*)d_in[2];
    const float* Wv = (const float*)d_in[3];
    const float* Wo = (const float*)d_in[4];
    const float* bo = (const float*)d_in[5];
    float* out = (float*)d_out;
    short* ws = (short*)d_ws;

    short* xb  = ws;              // [4096][1024] bf16 x
    short* wqb = ws + 4194304;
    short* wkb = ws + 5242880;
    short* wvb = ws + 6291456;
    short* wob = ws + 7340032;
    short* Qh  = ws + 8388608;    // [2][16][2048][64], scaled 0.125*log2e
    short* Kh  = ws + 12582912;   // [2][16][2048][64]
    short* Vf  = ws + 16777216;   // [32 bh][32 chunks][4096] PV-fragment order
    short* AO  = ws + 20971520;   // [4096][1024] attention output

    cvt_all_kernel<<<8192, 256, 0, stream>>>(x, Wq, Wk, Wv, Wo, ws);
    gemm_qkv_kernel<<<dim3(24, 64), 256, 0, stream>>>(xb, wqb, wkb, wvb, Qh, Kh, Vf);
    attn_kernel<<<1024, 256, 0, stream>>>(Qh, Kh, Vf, AO);
    gemm_out_kernel<<<dim3(8, 64), 256, 0, stream>>>(AO, wob, bo, out);
}

// Round 9
// 158.806 us; speedup vs baseline: 1.4233x; 1.0345x over previous
//
#include <hip/hip_runtime.h>
#include <hip/hip_bf16.h>

typedef __attribute__((ext_vector_type(8))) short bf16x8;
typedef __attribute__((ext_vector_type(4))) short short4v;
typedef __attribute__((ext_vector_type(4))) float f32x4;
typedef unsigned int u32;

// ---------- helpers ----------
__device__ __forceinline__ short f2bf(float f) {
    union { float f; u32 i; } c; c.f = f;
    u32 r = c.i + 0x7FFFu + ((c.i >> 16) & 1u);   // RNE
    return (short)(r >> 16);
}
__device__ __forceinline__ u32 pack2bf(float lo, float hi) {
    return ((u32)(unsigned short)f2bf(hi) << 16) | (u32)(unsigned short)f2bf(lo);
}
__device__ __forceinline__ f32x4 mfma16(bf16x8 a, bf16x8 b, f32x4 c) {
    return __builtin_amdgcn_mfma_f32_16x16x32_bf16(a, b, c, 0, 0, 0);
}
// K=16 MFMA: B-operand layout matches QK^T D-layout -> zero-shuffle PV.
__device__ __forceinline__ f32x4 mfma16k16(short4v a, short4v b, f32x4 c) {
#if __has_builtin(__builtin_amdgcn_mfma_f32_16x16x16bf16_1k)
    return __builtin_amdgcn_mfma_f32_16x16x16bf16_1k(a, b, c, 0, 0, 0);
#else
    f32x4 d = c;
    asm volatile("v_mfma_f32_16x16x16_bf16 %0, %1, %2, %0"
                 : "+v"(d) : "v"(a), "v"(b));
    return d;
#endif
}
// bare v_exp_f32 (exp2); logits kept in log2 domain (log2e folded into Q)
__device__ __forceinline__ float fexp2(float x) {
#if __has_builtin(__builtin_amdgcn_exp2f)
    return __builtin_amdgcn_exp2f(x);
#else
    float r; asm("v_exp_f32 %0, %1" : "=v"(r) : "v"(x)); return r;
#endif
}
__device__ __forceinline__ void load_lds16(const void* g, void* l) {
    __builtin_amdgcn_global_load_lds(
        (const __attribute__((address_space(1))) u32*)g,
        (__attribute__((address_space(3))) u32*)l, 16, 0, 0);
}

// ---------- fp32 -> bf16 convert (x + 4 weights fused) ----------
__global__ __launch_bounds__(256) void cvt_all_kernel(
    const float* __restrict__ x, const float* __restrict__ wq,
    const float* __restrict__ wk, const float* __restrict__ wv,
    const float* __restrict__ wo, short* __restrict__ ws) {
    const int XV = (4096 * 1024) / 4;
    const int WV = (1024 * 1024) / 4;
    int i = blockIdx.x * 256 + threadIdx.x;
    const float4* src; short4v* dst; int off;
    if (i < XV)            { src = (const float4*)x;  dst = (short4v*)(ws);           off = i; }
    else if (i < XV + WV)  { src = (const float4*)wq; dst = (short4v*)(ws + 4194304); off = i - XV; }
    else if (i < XV + 2*WV){ src = (const float4*)wk; dst = (short4v*)(ws + 5242880); off = i - XV - WV; }
    else if (i < XV + 3*WV){ src = (const float4*)wv; dst = (short4v*)(ws + 6291456); off = i - XV - 2*WV; }
    else                   { src = (const float4*)wo; dst = (short4v*)(ws + 7340032); off = i - XV - 3*WV; }
    float4 v = src[off];
    short4v o;
    o.x = f2bf(v.x); o.y = f2bf(v.y); o.z = f2bf(v.z); o.w = f2bf(v.w);
    dst[off] = o;
}

// ---------- shared GEMM mainloop (128x128 tile) ----------
__device__ __forceinline__ void gemm_mainloop(
    const short* __restrict__ A, const short* __restrict__ Bm,
    short* lds, int mbase, int nbase, int wave, int lane, f32x4 acc[4][4]) {
    const int K = 1024;
    const int lr = lane & 15, lg = lane >> 4;
    const int wm = wave >> 1, wn = wave & 1;
    for (int k0 = 0; k0 < K; k0 += 64) {
        __syncthreads();
        #pragma unroll
        for (int issue = 0; issue < 4; ++issue) {
            int f = issue * 4 + wave;
            int mt = f >> 1, kc = f & 1;
            load_lds16(A  + (size_t)(mbase + mt*16 + lr)*K + (k0 + kc*32 + lg*8), lds + f*512);
            load_lds16(Bm + (size_t)(nbase + mt*16 + lr)*K + (k0 + kc*32 + lg*8), lds + 8192 + f*512);
        }
        __syncthreads();
        #pragma unroll
        for (int kc = 0; kc < 2; ++kc) {
            bf16x8 af[4], bfv[4];
            #pragma unroll
            for (int mi = 0; mi < 4; ++mi)
                af[mi] = *(const bf16x8*)(lds + ((wm*4 + mi)*2 + kc)*512 + lane*8);
            #pragma unroll
            for (int ni = 0; ni < 4; ++ni)
                bfv[ni] = *(const bf16x8*)(lds + 8192 + ((wn*4 + ni)*2 + kc)*512 + lane*8);
            #pragma unroll
            for (int mi = 0; mi < 4; ++mi)
                #pragma unroll
                for (int ni = 0; ni < 4; ++ni)
                    acc[mi][ni] = mfma16(af[mi], bfv[ni], acc[mi][ni]);
        }
    }
}

// ---------- fused QKV projection (R6 measured-best 128x128 form) ----------
// Q scaled by 0.125*log2e (folds softmax scale AND exp->exp2 conversion).
// Q/K epilogue: LDS transpose -> 16-B coalesced stores into [bh][np][64].
// V epilogue: direct PV-fragment-order stores.
__global__ __launch_bounds__(256) void gemm_qkv_kernel(
    const short* __restrict__ xb, const short* __restrict__ wqb,
    const short* __restrict__ wkb, const short* __restrict__ wvb,
    short* __restrict__ Qh, short* __restrict__ Kh, short* __restrict__ Vf) {
    __shared__ short lds[16896];   // mainloop uses [0,16384); epilogue 128x132
    const int wave = threadIdx.x >> 6, lane = threadIdx.x & 63;
    const int lr = lane & 15, lg = lane >> 4;
    const int sel = blockIdx.x >> 3;
    const int nbase = (blockIdx.x & 7) * 128;
    const int mbase = blockIdx.y * 128;
    const short* Bm = (sel == 0) ? wqb : (sel == 1) ? wkb : wvb;

    f32x4 acc[4][4];
    #pragma unroll
    for (int i = 0; i < 4; ++i)
        #pragma unroll
        for (int j = 0; j < 4; ++j) acc[i][j] = f32x4{0.f, 0.f, 0.f, 0.f};

    gemm_mainloop(xb, Bm, lds, mbase, nbase, wave, lane, acc);

    const int wm = wave >> 1, wn = wave & 1;
    if (sel == 2) {
        #pragma unroll
        for (int mi = 0; mi < 4; ++mi) {
            int m0 = mbase + wm*64 + mi*16 + lg*4;
            #pragma unroll
            for (int ni = 0; ni < 4; ++ni) {
                int nc = nbase + wn*64 + ni*16 + lr;
                int h = nc >> 6, d = nc & 63;
                f32x4 v = acc[mi][ni];
                int bi = m0 >> 11, np = m0 & 2047;
                int c = np >> 6, s = (np >> 4) & 3, lg2 = (np >> 2) & 3;
                int dc = d >> 4, lr2 = d & 15;
                size_t off = ((size_t)(bi*16 + h)*32 + c)*4096
                           + (size_t)((s*4 + dc)*64 + lg2*16 + lr2)*4;
                short4v o;
                o.x = f2bf(v.x); o.y = f2bf(v.y); o.z = f2bf(v.z); o.w = f2bf(v.w);
                *(short4v*)&Vf[off] = o;
            }
        }
    } else {
        short* dstb = (sel == 0) ? Qh : Kh;
        const float sc = (sel == 0) ? 0.125f * 1.44269504f : 1.0f;
        __syncthreads();   // all mainloop LDS reads done before overwrite
        #pragma unroll
        for (int mi = 0; mi < 4; ++mi) {
            int row0 = wm*64 + mi*16 + lg*4;
            #pragma unroll
            for (int ni = 0; ni < 4; ++ni) {
                int col = wn*64 + ni*16 + lr;
                f32x4 v = acc[mi][ni];
                #pragma unroll
                for (int r = 0; r < 4; ++r)
                    lds[(row0 + r)*132 + col] = f2bf(v[r] * sc);
            }
        }
        __syncthreads();
        const int h0 = nbase >> 6;
        const int tid = threadIdx.x;
        #pragma unroll
        for (int it = 0; it < 8; ++it) {
            int L = it*256 + tid;          // 0..2047
            int np_l = L >> 4;             // 0..127
            int t16 = L & 15;
            int P = t16 >> 3;              // head panel 0/1
            int c8 = (t16 & 7) * 8;        // col in shorts
            bf16x8 val = *(const bf16x8*)&lds[np_l*132 + P*64 + c8];
            int m = mbase + np_l; int bi = m >> 11, np = m & 2047;
            *(bf16x8*)&dstb[((size_t)(bi*16 + h0 + P)*2048 + np)*64 + c8] = val;
        }
    }
}

// ---------- output projection: 64x128 tile (512 blocks = 2/CU) ----------
__global__ __launch_bounds__(256) void gemm_out_kernel(
    const short* __restrict__ AO, const short* __restrict__ wob,
    const float* __restrict__ bias, float* __restrict__ out) {
    __shared__ short lds[12288];
    const int K = 1024;
    const int wave = threadIdx.x >> 6, lane = threadIdx.x & 63;
    const int lr = lane & 15, lg = lane >> 4;
    const int nbase = blockIdx.x * 128;
    const int mbase = blockIdx.y * 64;
    const int wm = wave >> 1, wn = wave & 1;

    f32x4 acc[2][4];
    #pragma unroll
    for (int i = 0; i < 2; ++i)
        #pragma unroll
        for (int j = 0; j < 4; ++j) acc[i][j] = f32x4{0.f, 0.f, 0.f, 0.f};

    for (int k0 = 0; k0 < K; k0 += 64) {
        __syncthreads();
        #pragma unroll
        for (int l = 0; l < 6; ++l) {
            int f = l*4 + wave;
            if (f < 8) {
                int mt = f >> 1, kc = f & 1;
                load_lds16(AO + (size_t)(mbase + mt*16 + lr)*K + (k0 + kc*32 + lg*8),
                           lds + f*512);
            } else {
                int fb = f - 8, nt = fb >> 1, kc = fb & 1;
                load_lds16(wob + (size_t)(nbase + nt*16 + lr)*K + (k0 + kc*32 + lg*8),
                           lds + 4096 + fb*512);
            }
        }
        __syncthreads();
        #pragma unroll
        for (int kc = 0; kc < 2; ++kc) {
            bf16x8 af[2], bfv[4];
            #pragma unroll
            for (int mi = 0; mi < 2; ++mi)
                af[mi] = *(const bf16x8*)(lds + ((wm*2 + mi)*2 + kc)*512 + lane*8);
            #pragma unroll
            for (int ni = 0; ni < 4; ++ni)
                bfv[ni] = *(const bf16x8*)(lds + 4096 + ((wn*4 + ni)*2 + kc)*512 + lane*8);
            #pragma unroll
            for (int mi = 0; mi < 2; ++mi)
                #pragma unroll
                for (int ni = 0; ni < 4; ++ni)
                    acc[mi][ni] = mfma16(af[mi], bfv[ni], acc[mi][ni]);
        }
    }

    #pragma unroll
    for (int mi = 0; mi < 2; ++mi) {
        int m0 = mbase + wm*32 + mi*16 + lg*4;
        #pragma unroll
        for (int ni = 0; ni < 4; ++ni) {
            int nc = nbase + wn*64 + ni*16 + lr;
            float bj = bias[nc];
            f32x4 v = acc[mi][ni];
            #pragma unroll
            for (int r = 0; r < 4; ++r)
                out[(size_t)(m0 + r)*1024 + nc] = v[r] + bj;
        }
    }
}

// ---------- LDS-staged attention with COUNTED-vmcnt pipelining (T4) ----------
// Block = 64 q-rows (4 waves x 16). Per chunk: barrier_A (frees buffer being
// overwritten) -> issue c+1 global_load_lds -> s_waitcnt vmcnt(N) (waits only
// chunk c's loads; c+1 stays IN FLIGHT across the barrier) -> barrier_B ->
// compute. No vmcnt(0) drain in the steady-state loop. Zero-shuffle PV.
__global__ __launch_bounds__(256, 4) void attn_kernel(
    const short* __restrict__ Qh, const short* __restrict__ Kh,
    const short* __restrict__ Vf, short* __restrict__ AO) {
    __shared__ short lds[16384];   // K bufs [0,8192), V bufs [8192,16384)
    const int lane = threadIdx.x & 63;
    const int wave = threadIdx.x >> 6;
    const int lr = lane & 15, lg = lane >> 4;
    const int bid  = blockIdx.x;             // 0..1023
    const int xcd  = bid & 7;
    const int rest = bid >> 3;               // 0..127
    const int u    = 31 - (rest >> 2);       // heavy q-tiles dispatch first
    const int bh   = ((rest & 3) << 3) | xcd;
    const int b = bh >> 4, h = bh & 15;
    const int qbase = u*64 + wave*16;
    const int qa = qbase + lr;
    const short* Q  = Qh + (size_t)bh * (2048 * 64);
    const short* Kg = Kh + (size_t)bh * (2048 * 64);
    const short* Vg = Vf + (size_t)bh * (32 * 4096);

    bf16x8 qf0 = *(const bf16x8*)&Q[(size_t)qa*64 + lg*8];
    bf16x8 qf1 = *(const bf16x8*)&Q[(size_t)qa*64 + 32 + lg*8];

    const int fc0 = wave * 2;   // this wave's staging slots

    auto stageK = [&](int buf, int c) {
        #pragma unroll
        for (int i = 0; i < 2; ++i) {
            int fc = fc0 + i, s = fc >> 1, ch = fc & 1;
            load_lds16(Kg + ((size_t)(c*64 + s*16 + lr)*64 + ch*32 + lg*8),
                       &lds[buf*4096 + fc*512]);
        }
    };
    auto stageV = [&](int buf, int c) {
        #pragma unroll
        for (int i = 0; i < 2; ++i) {
            int fi = fc0 + i;
            load_lds16(Vg + (size_t)c*4096 + fi*512 + lane*8,
                       &lds[8192 + buf*4096 + fi*512]);
        }
    };

    // ================= pass 1: entropy stats =================
    float sm = 0.f, t2m = 0.f;
    stageK(0, 0);                              // 2 loads in flight
    #pragma unroll 1
    for (int c = 0; c <= u; ++c) {
        __builtin_amdgcn_s_barrier();          // A: all done reading buf (c+1)&1
        asm volatile("" ::: "memory");
        if (c < u) {
            stageK((c + 1) & 1, c + 1);        // 2 more in flight
            asm volatile("s_waitcnt vmcnt(2)" ::: "memory");  // c's loads landed
        } else {
            asm volatile("s_waitcnt vmcnt(0)" ::: "memory");
        }
        __builtin_amdgcn_s_barrier();          // B: everyone's c data landed
        asm volatile("" ::: "memory");
        const int base = (c & 1) * 4096;
        #pragma unroll
        for (int s = 0; s < 4; ++s) {
            int k0 = c*64 + s*16;
            if (k0 <= qbase) {                 // wave-uniform
                bf16x8 kf0 = *(const bf16x8*)&lds[base + (s*2    )*512 + lane*8];
                bf16x8 kf1 = *(const bf16x8*)&lds[base + (s*2 + 1)*512 + lane*8];
                f32x4 d = {0.f,0.f,0.f,0.f};
                d = mfma16(kf0, qf0, d); d = mfma16(kf1, qf1, d);
                if (k0 < qbase) {
                    #pragma unroll
                    for (int r = 0; r < 4; ++r) {
                        float e = fexp2(d[r]); sm += e; t2m += e * d[r];
                    }
                } else {                       // diagonal subtile
                    int kb = k0 + lg*4;
                    #pragma unroll
                    for (int r = 0; r < 4; ++r) {
                        float dd = (kb + r <= qa) ? d[r] : -1e30f;
                        float e = fexp2(dd); sm += e; t2m += e * dd;
                    }
                }
            }
        }
    }
    sm += __shfl_xor(sm, 16); t2m += __shfl_xor(t2m, 16);
    sm += __shfl_xor(sm, 32); t2m += __shfl_xor(t2m, 32);
    const float LN2 = 0.69314718f;
    float H = LN2 * (__log2f(sm) - t2m / sm);
    float beta = 1.f;
    if (H > 0.5f)
        beta = fmaxf((((-0.037f*H + 0.481f)*H - 2.3f)*H + 4.917f)*H - 1.791f, 1.f);

    // ================= pass 2: softmax(beta*d) and PV =================
    f32x4 o0 = {0.f,0.f,0.f,0.f}, o1 = {0.f,0.f,0.f,0.f};
    f32x4 o2 = {0.f,0.f,0.f,0.f}, o3 = {0.f,0.f,0.f,0.f};
    float s2 = 0.f;
    __syncthreads();                           // pass-1 reads done; reuse bufs
    stageK(0, 0); stageV(0, 0);                // 4 loads in flight
    #pragma unroll 1
    for (int c = 0; c <= u; ++c) {
        __builtin_amdgcn_s_barrier();          // A
        asm volatile("" ::: "memory");
        if (c < u) {
            stageK((c + 1) & 1, c + 1); stageV((c + 1) & 1, c + 1);
            asm volatile("s_waitcnt vmcnt(4)" ::: "memory");
        } else {
            asm volatile("s_waitcnt vmcnt(0)" ::: "memory");
        }
        __builtin_amdgcn_s_barrier();          // B
        asm volatile("" ::: "memory");
        const int kb_ = (c & 1) * 4096;
        const int vb_ = 8192 + (c & 1) * 4096;
        #pragma unroll
        for (int s = 0; s < 4; ++s) {
            int k0 = c*64 + s*16;
            if (k0 <= qbase) {
                bf16x8 kf0 = *(const bf16x8*)&lds[kb_ + (s*2    )*512 + lane*8];
                bf16x8 kf1 = *(const bf16x8*)&lds[kb_ + (s*2 + 1)*512 + lane*8];
                f32x4 d = {0.f,0.f,0.f,0.f};
                d = mfma16(kf0, qf0, d); d = mfma16(kf1, qf1, d);
                float pv[4];
                if (k0 < qbase) {
                    #pragma unroll
                    for (int r = 0; r < 4; ++r) { pv[r] = fexp2(beta * d[r]); s2 += pv[r]; }
                } else {
                    int kb = k0 + lg*4;
                    #pragma unroll
                    for (int r = 0; r < 4; ++r) {
                        float dd = (kb + r <= qa) ? d[r] : -1e30f;
                        pv[r] = fexp2(beta * dd); s2 += pv[r];
                    }
                }
                union { short4v s4; u32 uu[2]; } pb;
                pb.uu[0] = pack2bf(pv[0], pv[1]);
                pb.uu[1] = pack2bf(pv[2], pv[3]);
                short4v vf0 = *(const short4v*)&lds[vb_ + ((s*4 + 0)*64 + lane)*4];
                short4v vf1 = *(const short4v*)&lds[vb_ + ((s*4 + 1)*64 + lane)*4];
                short4v vf2 = *(const short4v*)&lds[vb_ + ((s*4 + 2)*64 + lane)*4];
                short4v vf3 = *(const short4v*)&lds[vb_ + ((s*4 + 3)*64 + lane)*4];
                o0 = mfma16k16(vf0, pb.s4, o0);
                o1 = mfma16k16(vf1, pb.s4, o1);
                o2 = mfma16k16(vf2, pb.s4, o2);
                o3 = mfma16k16(vf3, pb.s4, o3);
            }
        }
    }
    s2 += __shfl_xor(s2, 16); s2 += __shfl_xor(s2, 32);
    float inv = 1.f / s2;

    size_t row = ((size_t)(b*2048 + qa))*1024 + h*64;
    f32x4 oo[4] = {o0, o1, o2, o3};
    #pragma unroll
    for (int dc = 0; dc < 4; ++dc) {
        short4v wv;
        #pragma unroll
        for (int r = 0; r < 4; ++r) wv[r] = f2bf(oo[dc][r] * inv);
        *(short4v*)&AO[row + dc*16 + lg*4] = wv;
    }
}

// ---------- launch ----------
extern "C" void kernel_launch(void* const* d_in, const int* in_sizes, int n_in,
                              void* d_out, int out_size, void* d_ws, size_t ws_size,
                              hipStream_t stream) {
    const float* x  = (const float*)d_in[0];
    const float* Wq = (const float*)d_in[1];
    const float* Wk = (const float*)d_in[2];
    const float* Wv = (const float*)d_in[3];
    const float* Wo = (const float*)d_in[4];
    const float* bo = (const float*)d_in[5];
    float* out = (float*)d_out;
    short* ws = (short*)d_ws;

    short* xb  = ws;              // [4096][1024] bf16 x
    short* wqb = ws + 4194304;
    short* wkb = ws + 5242880;
    short* wvb = ws + 6291456;
    short* wob = ws + 7340032;
    short* Qh  = ws + 8388608;    // [2][16][2048][64], scaled 0.125*log2e
    short* Kh  = ws + 12582912;   // [2][16][2048][64]
    short* Vf  = ws + 16777216;   // [32 bh][32 chunks][4096] PV-fragment order
    short* AO  = ws + 20971520;   // [4096][1024] attention output

    cvt_all_kernel<<<8192, 256, 0, stream>>>(x, Wq, Wk, Wv, Wo, ws);
    gemm_qkv_kernel<<<dim3(24, 32), 256, 0, stream>>>(xb, wqb, wkb, wvb, Qh, Kh, Vf);
    attn_kernel<<<1024, 256, 0, stream>>>(Qh, Kh, Vf, AO);
    gemm_out_kernel<<<dim3(8, 64), 256, 0, stream>>>(AO, wob, bo, out);
}